// Round 1
// 268.233 us; speedup vs baseline: 1.1113x; 1.1113x over previous
//
#include <hip/hip_runtime.h>
#include <stdint.h>

// ResNetV1 sparse conv block, MI355X (gfx950).
// out = relu( conv(relu(conv(x,W0)), W1) + x ),  conv[n,d] = sum_k sum_c x[idx[n,k],c] * W[k,c,d]
// N=150000, K=27, C=64.
// R9 = R8 (111 us/conv) + cross-wave B sharing via LDS.
// Theory: L2 request-rate wall (~91 line-req/cyc chip vs ~128 port ceiling). Per wave-iter
// the B (weight) stream was 128 of 192 line-reqs, re-fetched per wave per k (1.04 GB/conv).
// Now: 4-wave block (128 rows) stages W[k] (8 KB) ONCE per k into double-buffered LDS via
// global_load_lds(16B), all waves ds_read it. 384 reqs per 128 rows = 3/row vs 6/row.
// Gathers issue BEFORE the stage so the compiler's counted vmcnt leaves the stage in
// flight across the MFMAs; the per-iter __syncthreads drain lands after a full compute
// phase. Decisive A/B: win => request-wall confirmed; neutral => random line-service wall.

typedef __attribute__((ext_vector_type(8))) short short8;
typedef __attribute__((ext_vector_type(4))) float f32x4;

#define NV 150000
#define KOFF 27

static __device__ __forceinline__ ushort f2bf(float f) {
  union { float f; uint32_t u; } v; v.f = f;
  uint32_t u = v.u;
  return (ushort)((u + 0x7fffu + ((u >> 16) & 1u)) >> 16);
}

// Fused prep: x -> bf16 (4/thread), then pack W0, W1 into B-fragment order.
// Pack map: flat = (((k*2+s)*4+ct)*64 + l)*8 + j <- W[k][c=s*32+(l>>4)*8+j][d=ct*16+(l&15)]
__global__ void prep_kernel(const float* __restrict__ x,
                            const float* __restrict__ W0,
                            const float* __restrict__ W1,
                            ushort* __restrict__ xb,
                            ushort* __restrict__ wp0,
                            ushort* __restrict__ wp1,
                            int nc4, int wtot) {
  int i = blockIdx.x * 256 + threadIdx.x;
  if (i < nc4) {
    float4 v = ((const float4*)x)[i];
    ushort4 o;
    o.x = f2bf(v.x); o.y = f2bf(v.y); o.z = f2bf(v.z); o.w = f2bf(v.w);
    ((ushort4*)xb)[i] = o;
    return;
  }
  int o = i - nc4;
  const float* W = W0;
  ushort* wp = wp0;
  if (o >= wtot) { o -= wtot; W = W1; wp = wp1; }
  if (o >= wtot) return;
  int j  = o & 7;
  int l  = (o >> 3) & 63;
  int ct = (o >> 9) & 3;
  int s  = (o >> 11) & 1;
  int k  = o >> 12;
  int c  = s * 32 + (l >> 4) * 8 + j;
  int d  = ct * 16 + (l & 15);
  wp[o] = f2bf(W[(k * 64 + c) * 64 + d]);
}

// 4-wave block, 128 rows (each wave: 32 rows = 2 x 16-row MFMA tiles).
// MODE 0: relu(conv) -> bf16. MODE 1: relu(conv+resid) -> fp32.
template <int MODE>
__global__ __launch_bounds__(256, 5) void conv_kernel(
    const ushort* __restrict__ feat,   // [N,64] bf16 bits
    const int*    __restrict__ nbr,    // [N,27]
    const ushort* __restrict__ wp,     // packed W, 27*4096 bf16
    const float*  __restrict__ resid,  // [N,64] fp32 (MODE 1)
    ushort*       __restrict__ out_bf, // MODE 0
    float*        __restrict__ out_f,  // MODE 1
    int n) {
  __shared__ __align__(16) int    sIdx[128 * KOFF];  // 128 rows x 27 offsets = 13824 B
  __shared__ __align__(16) ushort smB[2][4096];      // double-buffered W[k], 8 KB each

  const int tid  = threadIdx.x;       // 0..255
  const int lane = tid & 63;
  const int wid  = tid >> 6;          // wave 0..3
  const int quad = lane >> 4;
  const int lo   = lane & 15;
  const int mw   = blockIdx.x * 128 + wid * 32;

  // ---- Stage block's idx rows: nbr[bid*128*27 .. +3456), contiguous, coalesced int4.
  {
    const int total = n * KOFF;
    const int g0    = blockIdx.x * (128 * KOFF);
    #pragma unroll
    for (int u = 0; u < 3; ++u) {
      int j  = tid + 256 * u;          // int4 index 0..767
      int ai = g0 + 4 * j;
      ai = ai + 4 <= total ? ai : (total - 4);   // clamp (tail block only)
      ((int4*)sIdx)[j] = *(const int4*)(nbr + ai);
    }
    if (tid < 96) {                    // int4 indices 768..863
      int j  = 768 + tid;
      int ai = g0 + 4 * j;
      ai = ai + 4 <= total ? ai : (total - 4);
      ((int4*)sIdx)[j] = *(const int4*)(nbr + ai);
    }
  }

  // ---- Prologue: stage W[0] into buf 0 (each wave: 2 x 1KB chunks, direct-to-LDS).
  {
    #pragma unroll
    for (int u = 0; u < 2; ++u) {
      int c = wid * 2 + u;            // chunk 0..7, wave-uniform
      __builtin_amdgcn_global_load_lds(
          (const __attribute__((address_space(1))) void*)(wp + c * 512 + lane * 8),
          (__attribute__((address_space(3))) void*)(&smB[0][c * 512]), 16, 0, 0);
    }
  }
  __syncthreads();  // drains idx staging + B[0] stage (vmcnt+lgkm)

  int ioff[2];
  #pragma unroll
  for (int rt = 0; rt < 2; ++rt) ioff[rt] = (wid * 32 + rt * 16 + lo) * KOFF;

  f32x4 acc[2][4];
  #pragma unroll
  for (int rt = 0; rt < 2; ++rt)
    #pragma unroll
    for (int ct = 0; ct < 4; ++ct)
      acc[rt][ct] = (f32x4)0.0f;

  int gi[2];
  #pragma unroll
  for (int rt = 0; rt < 2; ++rt) {
    int g = sIdx[ioff[rt]];
    gi[rt] = g < n ? g : 0;           // clamped-tail safety
  }

  #pragma unroll 1
  for (int k = 0; k < KOFF; ++k) {
    const int buf = k & 1;
    // A gathers FIRST (oldest outstanding vmem -> MFMA waits vmcnt(2), stage stays in flight).
    short8 a[2][2];
    #pragma unroll
    for (int rt = 0; rt < 2; ++rt) {
      const ushort* rowp = feat + gi[rt] * 64 + quad * 8;
      a[rt][0] = *(const short8*)(rowp);
      a[rt][1] = *(const short8*)(rowp + 32);
    }
    __builtin_amdgcn_sched_barrier(0);  // keep stage issue AFTER the gathers
    // Stage next-k B into the other buffer; overlaps gather-wait + MFMA, drained at barrier.
    if (k + 1 < KOFF) {
      #pragma unroll
      for (int u = 0; u < 2; ++u) {
        int c = wid * 2 + u;
        __builtin_amdgcn_global_load_lds(
            (const __attribute__((address_space(1))) void*)(wp + (k + 1) * 4096 + c * 512 + lane * 8),
            (__attribute__((address_space(3))) void*)(&smB[buf ^ 1][c * 512]), 16, 0, 0);
      }
      // Next-k idx from LDS (conflict-free: 27*lo mod 32 distinct; same-lo broadcast).
      #pragma unroll
      for (int rt = 0; rt < 2; ++rt) gi[rt] = sIdx[ioff[rt] + k + 1];
    }
    // B fragments from LDS (shared by all 4 waves; was 8 KB of global per wave per k).
    const short8* bl = (const short8*)smB[buf];
    short8 b[8];
    #pragma unroll
    for (int t = 0; t < 8; ++t) b[t] = bl[t * 64 + lane];
    // 16 MFMAs.
    #pragma unroll
    for (int s = 0; s < 2; ++s)
      #pragma unroll
      for (int rt = 0; rt < 2; ++rt)
        #pragma unroll
        for (int ct = 0; ct < 4; ++ct)
          acc[rt][ct] = __builtin_amdgcn_mfma_f32_16x16x32_bf16(a[rt][s], b[s * 4 + ct], acc[rt][ct], 0, 0, 0);
    // WAR guard: all waves done reading smB[buf] before iter k+1 overwrites it (k+2 stage
    // targets buf again only after the NEXT barrier). Also drains the k+1 stage (complete).
    __syncthreads();
  }

  // Epilogue: acc[rt][ct][j] -> out[mw + rt*16 + quad*4 + j][ct*16 + lo]
  #pragma unroll
  for (int rt = 0; rt < 2; ++rt) {
    int rbase = mw + rt * 16 + quad * 4;
    #pragma unroll
    for (int ct = 0; ct < 4; ++ct) {
      int col = ct * 16 + lo;
      #pragma unroll
      for (int j = 0; j < 4; ++j) {
        int r = rbase + j;
        if (r < n) {
          float v = acc[rt][ct][j];
          if (MODE == 0) {
            v = v > 0.0f ? v : 0.0f;
            out_bf[r * 64 + col] = f2bf(v);
          } else {
            v += resid[r * 64 + col];
            v = v > 0.0f ? v : 0.0f;
            out_f[r * 64 + col] = v;
          }
        }
      }
    }
  }
}

extern "C" void kernel_launch(void* const* d_in, const int* in_sizes, int n_in,
                              void* d_out, int out_size, void* d_ws, size_t ws_size,
                              hipStream_t stream) {
  const float* x   = (const float*)d_in[0];
  const int*   nbr = (const int*)d_in[1];
  const float* W0  = (const float*)d_in[2];
  const float* W1  = (const float*)d_in[3];
  float* out = (float*)d_out;

  const int n    = NV;
  const int nc   = NV * 64;        // 9,600,000
  const int nc4  = nc / 4;         // 2,400,000
  const int wtot = KOFF * 4096;    // 110,592

  ushort* xb  = (ushort*)d_ws;
  ushort* yb  = xb + nc;
  ushort* wp0 = yb + nc;
  ushort* wp1 = wp0 + wtot;

  const int prep_units = nc4 + 2 * wtot;
  prep_kernel<<<(prep_units + 255) / 256, 256, 0, stream>>>(x, W0, W1, xb, wp0, wp1, nc4, wtot);

  const int grid = (n + 127) / 128;  // 1172 four-wave blocks
  conv_kernel<0><<<grid, 256, 0, stream>>>(xb, nbr, wp0, nullptr, yb, nullptr, n);
  conv_kernel<1><<<grid, 256, 0, stream>>>(yb, nbr, wp1, x, nullptr, out, n);
}